// Round 14
// baseline (199.711 us; speedup 1.0000x reference)
//
#include <hip/hip_runtime.h>
#include <hip/hip_bf16.h>

// attention_84464826843938: additive-attention pooling, MI355X (gfx950)
//
// R14: ZERO-BARRIER single-wave blocks. R2/R7/R10/R13 all pin at 82-85us with
// every pipe idle -> the block-wide {load burst, barrier+waitcnt drain,
// compute} lockstep itself is the invariant (~6300cyc/step). Remove it:
// one wave = one (b, 64-col slice); wave-private 8KB frg buffer; LDS ops of a
// single wave execute in program order -> NO barriers, NO inline asm; the
// compiler inserts exact lgkm/vmcnt. 8 independent waves/CU drift freely and
// hide each other's latency (true asynchrony instead of hand-timed schedule).
//  grid = 8 slices x 256 b slice-major (XCD-local A re-read), 2048 blocks of
//  64 thr; ~225 VGPR -> 2 waves/SIMD, all co-resident.
//  Per step k: issue B(k+1) -> ds_read frg(k) -> cvt+ds_write(k+1) (reg-staged
//  A, 1 step ahead) -> issue A(k+2) -> 32 MFMA. x2-unrolled B sets (bE/bO).
//  frg layout kc*64+(row^kc) / staging geometry copied from R13 (0 conflicts).

#define B_ 256
#define R_ 64
#define F_ 2048
#define H_ 512
#define DIM_ 512

typedef short bf16x8 __attribute__((ext_vector_type(8)));
typedef float f32x4 __attribute__((ext_vector_type(4)));

__device__ __forceinline__ ushort f2bf(float x) {
  __hip_bfloat16 h = __float2bfloat16(x);
  return __builtin_bit_cast(ushort, h);
}

__device__ __forceinline__ uint2 pack4(float4 x) {
  uint2 r;
  r.x = (uint)f2bf(x.x) | ((uint)f2bf(x.y) << 16);
  r.y = (uint)f2bf(x.z) | ((uint)f2bf(x.w) << 16);
  return r;
}

// blocks [0,4096): wpack[((kt*32+ctg)*64 + g*16 + c)*8 + i] = bf16(W_w[kt*32+g*8+i][ctg*16+c])
// blocks [4096,4352): p'[b][d] = prev[b]@W2_w[:,d] + W2_b[d] + W_b[d]
__global__ __launch_bounds__(256) void setup_k(const float* __restrict__ Ww,
                                               ushort* __restrict__ wpack,
                                               const float* __restrict__ prev,
                                               const float* __restrict__ W2w,
                                               const float* __restrict__ W2b,
                                               const float* __restrict__ Wb,
                                               float* __restrict__ pprime) {
  __shared__ float lprev[8][H_];
  if (blockIdx.x < 4096) {
    int idx = blockIdx.x * 256 + threadIdx.x;
    float v = Ww[idx];
    int k = idx >> 9;
    int d = idx & 511;
    int kt = k >> 5, kr = k & 31;
    int g = kr >> 3, i = kr & 7;
    int ctg = d >> 4, c = d & 15;
    size_t dst = ((size_t)((kt * 32 + ctg) * 64 + g * 16 + c)) * 8 + (size_t)i;
    wpack[dst] = f2bf(v);
    return;
  }
  int pb = blockIdx.x - 4096;
  int bg = pb >> 3;
  int d0 = (pb & 7) * 64;
  int t = threadIdx.x;
  const float4* src = reinterpret_cast<const float4*>(prev + (size_t)bg * 8 * H_);
  float4* dst = reinterpret_cast<float4*>(&lprev[0][0]);
  for (int i = t; i < 8 * H_ / 4; i += 256) dst[i] = src[i];
  __syncthreads();
  int d = d0 + (t & 63);
  int bq = t >> 6;
  float a0 = 0.f, a1 = 0.f;
  #pragma unroll 8
  for (int h = 0; h < H_; ++h) {
    float wv = W2w[h * DIM_ + d];
    a0 += lprev[bq][h] * wv;
    a1 += lprev[bq + 4][h] * wv;
  }
  float bias = W2b[d] + Wb[d];
  pprime[(size_t)(bg * 8 + bq) * DIM_ + d] = a0 + bias;
  pprime[(size_t)(bg * 8 + bq + 4) * DIM_ + d] = a1 + bias;
}

__device__ __forceinline__ float fast_tanh(float x) {
  float e = __expf(2.f * x);
  return 1.f - 2.f / (e + 1.f);
}

// One wave per block. sp[(b*8+slice)*64 + r] = partial score over slice's 64 cols.
__global__ __launch_bounds__(64, 2) void score_k(const float* __restrict__ feat,
                                                 const ushort* __restrict__ wpack,
                                                 const float* __restrict__ pprime,
                                                 const float* __restrict__ W3,
                                                 float* __restrict__ sp) {
  int slice = blockIdx.x >> 8;          // slice-major: all 8 slices of b same XCD
  int b = blockIdx.x & 255;
  int l = threadIdx.x;
  int l15 = l & 15, g = l >> 4;
  const float* featB = feat + (size_t)b * R_ * F_;

  // frg[kc*64 + (row ^ kc)] = bf16 A[row][k = kt*64 + kc*8 .. +8]  (8 KB)
  __shared__ uint4 frg[512];
  __shared__ float sc[R_];

  f32x4 acc[4][4];
  #pragma unroll
  for (int rt = 0; rt < 4; ++rt)
    #pragma unroll
    for (int ct = 0; ct < 4; ++ct)
      acc[rt][ct] = (f32x4){0.f, 0.f, 0.f, 0.f};

  // A staging: lane l covers float4-chunk c4 = l&15 of rows r4+4j (j=0..15)
  int c4 = l & 15, r4 = l >> 4;
  int kcw = c4 >> 1, half = c4 & 1;
  const float* aptr = featB + (size_t)r4 * F_ + (size_t)(c4 * 4);
  float4 rA[16];

  // B: frag(kt,s,ct) at wp + kt*32768 + s*16384 + ct*512 (ushort units)
  const ushort* wp = wpack + (size_t)(slice * 4) * 512 + (size_t)l * 8;

#define LOADA(kt) do {                                               \
    _Pragma("unroll")                                                \
    for (int j_ = 0; j_ < 16; ++j_)                                  \
      rA[j_] = *reinterpret_cast<const float4*>(                     \
          aptr + (size_t)(j_ * 4) * F_ + (size_t)(kt) * 64);         \
  } while (0)

#define CVTW() do {                                                  \
    _Pragma("unroll")                                                \
    for (int j_ = 0; j_ < 16; ++j_) {                                \
      int row_ = r4 + 4 * j_;                                        \
      uint2* d_ = reinterpret_cast<uint2*>(&frg[kcw * 64 + (row_ ^ kcw)]); \
      d_[half] = pack4(rA[j_]);                                      \
    }                                                                \
  } while (0)

#define LOADB(dst, kt) do {                                          \
    const ushort* wpk_ = wp + (size_t)(kt) * 32768;                  \
    _Pragma("unroll")                                                \
    for (int s_ = 0; s_ < 2; ++s_)                                   \
      _Pragma("unroll")                                              \
      for (int ct_ = 0; ct_ < 4; ++ct_)                              \
        dst[s_ * 4 + ct_] = *reinterpret_cast<const uint4*>(         \
            wpk_ + s_ * 16384 + ct_ * 512);                          \
  } while (0)

#define STEP(k, BUSE, BNXT) do {                                     \
    if ((k) < 31) LOADB(BNXT, (k) + 1);                              \
    uint4 af0_[4], af1_[4];                                          \
    _Pragma("unroll")                                                \
    for (int rt_ = 0; rt_ < 4; ++rt_)                                \
      af0_[rt_] = frg[g * 64 + ((rt_ * 16 + l15) ^ g)];              \
    _Pragma("unroll")                                                \
    for (int rt_ = 0; rt_ < 4; ++rt_) {                              \
      int kc_ = 4 + g;                                               \
      af1_[rt_] = frg[kc_ * 64 + ((rt_ * 16 + l15) ^ kc_)];          \
    }                                                                \
    if ((k) < 31) CVTW();            /* write tile k+1 (LDS in-order after reads) */ \
    if ((k) < 30) LOADA((k) + 2);                                    \
    _Pragma("unroll")                                                \
    for (int ct_ = 0; ct_ < 4; ++ct_) {                              \
      bf16x8 bv_ = __builtin_bit_cast(bf16x8, BUSE[ct_]);            \
      _Pragma("unroll")                                              \
      for (int rt_ = 0; rt_ < 4; ++rt_)                              \
        acc[rt_][ct_] = __builtin_amdgcn_mfma_f32_16x16x32_bf16(     \
            __builtin_bit_cast(bf16x8, af0_[rt_]), bv_, acc[rt_][ct_], 0, 0, 0); \
    }                                                                \
    _Pragma("unroll")                                                \
    for (int ct_ = 0; ct_ < 4; ++ct_) {                              \
      bf16x8 bv_ = __builtin_bit_cast(bf16x8, BUSE[4 + ct_]);        \
      _Pragma("unroll")                                              \
      for (int rt_ = 0; rt_ < 4; ++rt_)                              \
        acc[rt_][ct_] = __builtin_amdgcn_mfma_f32_16x16x32_bf16(     \
            __builtin_bit_cast(bf16x8, af1_[rt_]), bv_, acc[rt_][ct_], 0, 0, 0); \
    }                                                                \
  } while (0)

  uint4 bE[8], bO[8];
  // prologue: A(0) -> rA; B(0) -> bE; cvt tile0; A(1) -> rA
  LOADA(0);
  LOADB(bE, 0);
  CVTW();
  LOADA(1);

  #pragma unroll 1
  for (int k = 0; k < 32; k += 2) {
    STEP(k, bE, bO);
    STEP(k + 1, bO, bE);
  }

#undef LOADA
#undef CVTW
#undef LOADB
#undef STEP

  // epilogue: tanh + W3 dot
  // acc[rt][ct][j] = c[row = rt*16 + g*4 + j][col = slice*64 + ct*16 + l15]
  float pp[4], w3v[4];
  #pragma unroll
  for (int ct = 0; ct < 4; ++ct) {
    int col = slice * 64 + ct * 16 + l15;
    pp[ct] = pprime[b * DIM_ + col];
    w3v[ct] = W3[col];
  }
  #pragma unroll
  for (int rt = 0; rt < 4; ++rt) {
    #pragma unroll
    for (int j = 0; j < 4; ++j) {
      float v = fast_tanh(acc[rt][0][j] + pp[0]) * w3v[0]
              + fast_tanh(acc[rt][1][j] + pp[1]) * w3v[1]
              + fast_tanh(acc[rt][2][j] + pp[2]) * w3v[2]
              + fast_tanh(acc[rt][3][j] + pp[3]) * w3v[3];
      v += __shfl_xor(v, 1);
      v += __shfl_xor(v, 2);
      v += __shfl_xor(v, 4);
      v += __shfl_xor(v, 8);
      if (l15 == 0) sc[rt * 16 + g * 4 + j] = v;
    }
  }
  // same-wave LDS: program order; compiler inserts lgkmcnt before read
  sp[((size_t)b * 8 + slice) * R_ + l] = sc[l];
}

// softmax + weighted sum: grid = B*4, 256 thr, 512 f per block
__global__ __launch_bounds__(256) void wsum_k(const float* __restrict__ feat,
                                              const float* __restrict__ sp,
                                              float* __restrict__ out) {
  int b = blockIdx.x >> 2;
  int f0 = (blockIdx.x & 3) * 512;
  int t = threadIdx.x;
  __shared__ float lds_aw[R_];

  if (t < R_) {
    float s = 0.f;
    #pragma unroll
    for (int i = 0; i < 8; ++i) s += sp[((size_t)b * 8 + i) * R_ + t];
    float m = s;
    #pragma unroll
    for (int off = 32; off >= 1; off >>= 1) m = fmaxf(m, __shfl_xor(m, off));
    float e = __expf(s - m);
    float su = e;
    #pragma unroll
    for (int off = 32; off >= 1; off >>= 1) su += __shfl_xor(su, off);
    lds_aw[t] = e / su;
  }
  __syncthreads();

  const float* fp = feat + (size_t)b * R_ * F_ + f0 + t * 2;
  float qx = 0.f, qy = 0.f;
  #pragma unroll 8
  for (int r = 0; r < R_; ++r) {
    float a = lds_aw[r];
    float2 v = *reinterpret_cast<const float2*>(fp + (size_t)r * F_);
    qx += a * v.x;
    qy += a * v.y;
  }
  *reinterpret_cast<float2*>(out + (size_t)b * F_ + f0 + t * 2) = (float2){qx, qy};
}

extern "C" void kernel_launch(void* const* d_in, const int* in_sizes, int n_in,
                              void* d_out, int out_size, void* d_ws, size_t ws_size,
                              hipStream_t stream) {
  const float* feat = (const float*)d_in[0];   // [B,R,F]
  const float* prev = (const float*)d_in[1];   // [B,H]
  const float* Ww   = (const float*)d_in[2];   // [F,DIM]
  const float* Wb   = (const float*)d_in[3];   // [DIM]
  const float* W2w  = (const float*)d_in[4];   // [H,DIM]
  const float* W2b  = (const float*)d_in[5];   // [DIM]
  const float* W3w  = (const float*)d_in[6];   // [DIM,1]
  // d_in[7] = W3_b: cancels in softmax
  float* out = (float*)d_out;

  ushort* wpack  = (ushort*)d_ws;                                          // 2 MB
  float*  pprime = (float*)((char*)d_ws + (size_t)F_ * DIM_ * 2);          // 512 KB
  float*  sp     = (float*)((char*)d_ws + (size_t)F_ * DIM_ * 2
                                        + (size_t)B_ * DIM_ * 4);          // 512 KB

  setup_k<<<4096 + 256, 256, 0, stream>>>(Ww, wpack, prev, W2w, W2b, Wb, pprime);
  score_k<<<B_ * 8, 64, 0, stream>>>(feat, wpack, pprime, W3w, sp);
  wsum_k<<<B_ * 4, 256, 0, stream>>>(feat, sp, out);
}

// Round 15
// 161.245 us; speedup vs baseline: 1.2386x; 1.2386x over previous
//
#include <hip/hip_runtime.h>
#include <hip/hip_bf16.h>

// attention_84464826843938: additive-attention pooling, MI355X (gfx950)
//
// R15: R10's score_k (best: 82us) VERBATIM + fused wsum tail.
//  score_k invariant (82-85us) survived 13 structural experiments (occupancy,
//  vmcnt, phasing, LDS traffic, barrier removal) -> stop optimizing the inner
//  loop; shave the 16us non-score tail instead. Both slices of b are
//  XCD-colocated; each block publishes sp, threadfence, atomic ACQ_REL on
//  cnt[b]; the SECOND arriver does softmax + q = aw^T feat[b] (L2/L3-warm).
//  wsum_k launch deleted. cnt zeroed via hipMemsetAsync (capture-legal).

#define B_ 256
#define R_ 64
#define F_ 2048
#define H_ 512
#define DIM_ 512

typedef short bf16x8 __attribute__((ext_vector_type(8)));
typedef float f32x4 __attribute__((ext_vector_type(4)));

__device__ __forceinline__ ushort f2bf(float x) {
  __hip_bfloat16 h = __float2bfloat16(x);
  return __builtin_bit_cast(ushort, h);
}

__device__ __forceinline__ uint4 pack8(float4 x, float4 y) {
  uint4 r;
  r.x = (uint)f2bf(x.x) | ((uint)f2bf(x.y) << 16);
  r.y = (uint)f2bf(x.z) | ((uint)f2bf(x.w) << 16);
  r.z = (uint)f2bf(y.x) | ((uint)f2bf(y.y) << 16);
  r.w = (uint)f2bf(y.z) | ((uint)f2bf(y.w) << 16);
  return r;
}

__device__ __forceinline__ void gld16(const float* g, float* l) {
  __builtin_amdgcn_global_load_lds(
      (const __attribute__((address_space(1))) unsigned int*)(g),
      (__attribute__((address_space(3))) unsigned int*)(l),
      16, 0, 0);
}

// blocks [0,4096): wpack[((kt*32+ctg)*64 + g*16 + c)*8 + i] = bf16(W_w[kt*32+g*8+i][ctg*16+c])
// blocks [4096,4352): p'[b][d] = prev[b]@W2_w[:,d] + W2_b[d] + W_b[d]
__global__ __launch_bounds__(256) void setup_k(const float* __restrict__ Ww,
                                               ushort* __restrict__ wpack,
                                               const float* __restrict__ prev,
                                               const float* __restrict__ W2w,
                                               const float* __restrict__ W2b,
                                               const float* __restrict__ Wb,
                                               float* __restrict__ pprime) {
  __shared__ float lprev[8][H_];
  if (blockIdx.x < 4096) {
    int idx = blockIdx.x * 256 + threadIdx.x;
    float v = Ww[idx];
    int k = idx >> 9;
    int d = idx & 511;
    int kt = k >> 5, kr = k & 31;
    int g = kr >> 3, i = kr & 7;
    int ctg = d >> 4, c = d & 15;
    size_t dst = ((size_t)((kt * 32 + ctg) * 64 + g * 16 + c)) * 8 + (size_t)i;
    wpack[dst] = f2bf(v);
    return;
  }
  int pb = blockIdx.x - 4096;
  int bg = pb >> 3;
  int d0 = (pb & 7) * 64;
  int t = threadIdx.x;
  const float4* src = reinterpret_cast<const float4*>(prev + (size_t)bg * 8 * H_);
  float4* dst = reinterpret_cast<float4*>(&lprev[0][0]);
  for (int i = t; i < 8 * H_ / 4; i += 256) dst[i] = src[i];
  __syncthreads();
  int d = d0 + (t & 63);
  int bq = t >> 6;
  float a0 = 0.f, a1 = 0.f;
  #pragma unroll 8
  for (int h = 0; h < H_; ++h) {
    float wv = W2w[h * DIM_ + d];
    a0 += lprev[bq][h] * wv;
    a1 += lprev[bq + 4][h] * wv;
  }
  float bias = W2b[d] + Wb[d];
  pprime[(size_t)(bg * 8 + bq) * DIM_ + d] = a0 + bias;
  pprime[(size_t)(bg * 8 + bq + 4) * DIM_ + d] = a1 + bias;
}

__device__ __forceinline__ float fast_tanh(float x) {
  float e = __expf(2.f * x);
  return 1.f - 2.f / (e + 1.f);
}

// sp[b*2+slice][r] partial scores; second-finishing block of each b does
// softmax + weighted sum (fused wsum).
__global__ __launch_bounds__(512, 4) void score_k(const float* __restrict__ feat,
                                                  const ushort* __restrict__ wpack,
                                                  const float* __restrict__ pprime,
                                                  const float* __restrict__ W3,
                                                  float* __restrict__ sp,
                                                  int* __restrict__ cnt,
                                                  float* __restrict__ out) {
  int slice = blockIdx.x >> 8;          // slice-major: both slices of b same XCD
  int b = blockIdx.x & 255;
  int t = threadIdx.x;
  int wid = t >> 6;                     // 8 waves; wave owns cols [wid*32,+32)
  int l = t & 63;
  int l15 = l & 15, g = l >> 4;
  const float* featB = feat + (size_t)b * R_ * F_;

  // raw[buf][row][c16]: holds global 16B-chunk (c16 ^ (row&15))  [src-swizzle]
  __shared__ float raw[3][4096];        // 3 x 16 KB DMA ring
  // frg[buf][kc*64 + (row ^ ((kc*2)&15))] = bf16 A[row][k=kc*8..+8]
  __shared__ uint4 frg[2][512];         // 2 x 8 KB
  __shared__ float lds_part[8][R_];
  __shared__ float lds_aw[R_];
  __shared__ int is_last;

  f32x4 acc[4][2];
  #pragma unroll
  for (int rt = 0; rt < 4; ++rt)
    #pragma unroll
    for (int ct = 0; ct < 2; ++ct)
      acc[rt][ct] = (f32x4){0.f, 0.f, 0.f, 0.f};

  // ---- DMA geometry: wave wid covers rows [wid*4, wid*4+4) and +32
  int srow = wid * 4 + g;
  int sch = l15 ^ (srow & 15);
  const float* sg0 = featB + (size_t)srow * F_ + sch * 4;
  const float* sg1 = featB + (size_t)(srow + 32) * F_ + sch * 4;

  // ---- cvt geometry: thread t -> row t>>3, k-chunk pair cj2 = (t&7)*2
  int crow = t >> 3, cj2 = (t & 7) * 2;
  int rm = crow & 15;
  int cw = (t & 7) * 64 + (crow ^ cj2);

  // ---- B pointer: frag(kt,s,ct) at wp + kt*32768 + s*16384 + ct*512 (ushorts)
  const ushort* wp = wpack + (size_t)(slice * 16 + wid * 2) * 512 + (size_t)l * 8;

#define STAGE(buf, kt) do {                                        \
    gld16(sg0 + (size_t)(kt) * 64, &raw[buf][wid * 256]);          \
    gld16(sg1 + (size_t)(kt) * 64, &raw[buf][2048 + wid * 256]);   \
  } while (0)

#define LOADB(dst, kt) do {                                        \
    const ushort* wpk_ = wp + (size_t)(kt) * 32768;                \
    dst[0][0] = *reinterpret_cast<const uint4*>(wpk_);             \
    dst[0][1] = *reinterpret_cast<const uint4*>(wpk_ + 512);       \
    dst[1][0] = *reinterpret_cast<const uint4*>(wpk_ + 16384);     \
    dst[1][1] = *reinterpret_cast<const uint4*>(wpk_ + 16384 + 512); \
  } while (0)

#define CVT(nb, fb) do {                                           \
    const float* rb_ = &raw[nb][crow * 64];                        \
    float4 x_ = *reinterpret_cast<const float4*>(rb_ + ((cj2 + 0) ^ rm) * 4); \
    float4 y_ = *reinterpret_cast<const float4*>(rb_ + ((cj2 + 1) ^ rm) * 4); \
    frg[fb][cw] = pack8(x_, y_);                                   \
  } while (0)

#define MFMA_STEP(fb, BSET) do {                                   \
    _Pragma("unroll")                                              \
    for (int s_ = 0; s_ < 2; ++s_) {                               \
      bf16x8 af_[4];                                               \
      int kc_ = s_ * 4 + g;                                        \
      _Pragma("unroll")                                            \
      for (int rt_ = 0; rt_ < 4; ++rt_)                            \
        af_[rt_] = __builtin_bit_cast(bf16x8,                      \
            frg[fb][kc_ * 64 + ((rt_ * 16 + l15) ^ ((kc_ * 2) & 15))]); \
      _Pragma("unroll")                                            \
      for (int ct_ = 0; ct_ < 2; ++ct_) {                          \
        bf16x8 bv_ = __builtin_bit_cast(bf16x8, BSET[s_][ct_]);    \
        _Pragma("unroll")                                          \
        for (int rt_ = 0; rt_ < 4; ++rt_)                          \
          acc[rt_][ct_] = __builtin_amdgcn_mfma_f32_16x16x32_bf16( \
              af_[rt_], bv_, acc[rt_][ct_], 0, 0, 0);              \
      }                                                            \
    }                                                              \
  } while (0)

#define BARRIER_VM(N) do {                                         \
    asm volatile("s_waitcnt vmcnt(" #N ") lgkmcnt(0)" ::: "memory"); \
    __builtin_amdgcn_s_barrier();                                  \
    asm volatile("" ::: "memory");                                 \
  } while (0)

  uint4 bA[2][2], bB[2][2];
  // prologue: D0, D1 in flight; bA=B(0). Drain D0 (keep D1+bA=6), publish raw0.
  STAGE(0, 0);
  STAGE(1, 1);
  LOADB(bA, 0);
  asm volatile("s_waitcnt vmcnt(6)" ::: "memory");
  __builtin_amdgcn_s_barrier();
  asm volatile("" ::: "memory");
  STAGE(2, 2);
  CVT(0, 0);                            // tile 0 -> frg[0]

  int st_b = 0, cv_b = 1;
  for (int e = 0; e < 28; e += 2) {
    LOADB(bB, e + 1);
    BARRIER_VM(10);
    STAGE(st_b, e + 3);
    CVT(cv_b, 1);
    __builtin_amdgcn_s_setprio(1);
    MFMA_STEP(0, bA);
    __builtin_amdgcn_s_setprio(0);
    st_b = (st_b == 2) ? 0 : st_b + 1;
    cv_b = (cv_b == 2) ? 0 : cv_b + 1;
    LOADB(bA, e + 2);
    BARRIER_VM(10);
    STAGE(st_b, e + 4);
    CVT(cv_b, 0);
    __builtin_amdgcn_s_setprio(1);
    MFMA_STEP(1, bB);
    __builtin_amdgcn_s_setprio(0);
    st_b = (st_b == 2) ? 0 : st_b + 1;
    cv_b = (cv_b == 2) ? 0 : cv_b + 1;
  }
  // peel e=28..31
  LOADB(bB, 29);
  BARRIER_VM(10);
  STAGE(1, 31);
  CVT(2, 1);
  __builtin_amdgcn_s_setprio(1);
  MFMA_STEP(0, bA);
  __builtin_amdgcn_s_setprio(0);
  LOADB(bA, 30);
  BARRIER_VM(10);
  CVT(0, 0);
  __builtin_amdgcn_s_setprio(1);
  MFMA_STEP(1, bB);
  __builtin_amdgcn_s_setprio(0);
  LOADB(bB, 31);
  BARRIER_VM(8);
  CVT(1, 1);
  __builtin_amdgcn_s_setprio(1);
  MFMA_STEP(0, bA);
  __builtin_amdgcn_s_setprio(0);
  BARRIER_VM(0);
  __builtin_amdgcn_s_setprio(1);
  MFMA_STEP(1, bB);
  __builtin_amdgcn_s_setprio(0);

#undef STAGE
#undef LOADB
#undef CVT
#undef MFMA_STEP
#undef BARRIER_VM

  // epilogue: tanh + W3 dot in registers
  float pp[2], w3v[2];
  #pragma unroll
  for (int ct = 0; ct < 2; ++ct) {
    int col = slice * 256 + wid * 32 + ct * 16 + l15;
    pp[ct] = pprime[b * DIM_ + col];
    w3v[ct] = W3[col];
  }
  #pragma unroll
  for (int rt = 0; rt < 4; ++rt) {
    #pragma unroll
    for (int j = 0; j < 4; ++j) {
      float v = fast_tanh(acc[rt][0][j] + pp[0]) * w3v[0]
              + fast_tanh(acc[rt][1][j] + pp[1]) * w3v[1];
      v += __shfl_xor(v, 1);
      v += __shfl_xor(v, 2);
      v += __shfl_xor(v, 4);
      v += __shfl_xor(v, 8);
      if (l15 == 0) lds_part[wid][rt * 16 + g * 4 + j] = v;
    }
  }
  __syncthreads();

  if (t < R_) {
    float s = 0.f;
    #pragma unroll
    for (int w = 0; w < 8; ++w) s += lds_part[w][t];
    sp[((size_t)b * 2 + slice) * R_ + t] = s;
  }
  __threadfence();                      // publish sp device-wide
  __syncthreads();

  // ---- last-block-wins fused wsum ----
  if (t == 0) {
    int old = __hip_atomic_fetch_add(&cnt[b], 1, __ATOMIC_ACQ_REL,
                                     __HIP_MEMORY_SCOPE_AGENT);
    is_last = (old == 1);
  }
  __syncthreads();
  if (!is_last) return;

  if (t < R_) {
    float s0 = __hip_atomic_load(&sp[((size_t)b * 2 + 0) * R_ + t],
                                 __ATOMIC_RELAXED, __HIP_MEMORY_SCOPE_AGENT);
    float s1 = __hip_atomic_load(&sp[((size_t)b * 2 + 1) * R_ + t],
                                 __ATOMIC_RELAXED, __HIP_MEMORY_SCOPE_AGENT);
    float s = s0 + s1;
    float m = s;
    #pragma unroll
    for (int off = 32; off >= 1; off >>= 1) m = fmaxf(m, __shfl_xor(m, off));
    float e = __expf(s - m);
    float su = e;
    #pragma unroll
    for (int off = 32; off >= 1; off >>= 1) su += __shfl_xor(su, off);
    lds_aw[t] = e / su;
  }
  __syncthreads();

  {
    int f0 = t * 4;                     // 512 thr x 4 cols = 2048
    float4 qa = (float4){0.f, 0.f, 0.f, 0.f};
    const float* fp = featB + f0;
    #pragma unroll 8
    for (int r = 0; r < R_; ++r) {
      float a = lds_aw[r];
      float4 v = *reinterpret_cast<const float4*>(fp + (size_t)r * F_);
      qa.x += a * v.x; qa.y += a * v.y; qa.z += a * v.z; qa.w += a * v.w;
    }
    *reinterpret_cast<float4*>(out + (size_t)b * F_ + f0) = qa;
  }
}

extern "C" void kernel_launch(void* const* d_in, const int* in_sizes, int n_in,
                              void* d_out, int out_size, void* d_ws, size_t ws_size,
                              hipStream_t stream) {
  const float* feat = (const float*)d_in[0];   // [B,R,F]
  const float* prev = (const float*)d_in[1];   // [B,H]
  const float* Ww   = (const float*)d_in[2];   // [F,DIM]
  const float* Wb   = (const float*)d_in[3];   // [DIM]
  const float* W2w  = (const float*)d_in[4];   // [H,DIM]
  const float* W2b  = (const float*)d_in[5];   // [DIM]
  const float* W3w  = (const float*)d_in[6];   // [DIM,1]
  // d_in[7] = W3_b: cancels in softmax
  float* out = (float*)d_out;

  char* ws = (char*)d_ws;
  ushort* wpack  = (ushort*)ws;                                   // 2 MB
  float*  pprime = (float*)(ws + (size_t)F_ * DIM_ * 2);          // 512 KB
  float*  sp     = (float*)(ws + (size_t)F_ * DIM_ * 2
                               + (size_t)B_ * DIM_ * 4);          // 128 KB
  int*    cnt    = (int*)(ws + (size_t)F_ * DIM_ * 2
                             + (size_t)B_ * DIM_ * 4
                             + (size_t)B_ * 2 * R_ * 4);          // 1 KB

  hipMemsetAsync(cnt, 0, B_ * sizeof(int), stream);
  setup_k<<<4096 + 256, 256, 0, stream>>>(Ww, wpack, prev, W2w, W2b, Wb, pprime);
  score_k<<<B_ * 2, 512, 0, stream>>>(feat, wpack, pprime, W3w, sp, cnt, out);
}

// Round 16
// 110.838 us; speedup vs baseline: 1.8018x; 1.4548x over previous
//
#include <hip/hip_runtime.h>
#include <hip/hip_bf16.h>

// attention_84464826843938: additive-attention pooling, MI355X (gfx950)
//
// R16: R10 + per-block K-rotation (single-variable experiment).
//  R15 postmortem: device-scope fence/atomic tail invalidated L2 for all
//  blocks (FETCH +65MB, MfmaUtil halved) -> reverted; wsum_k restored.
//  Hypothesis: all 512 blocks read the SAME 32KB wpack region in lockstep
//  each K-step -> L2 bank/channel hot-spotting (explains insensitivity to
//  occupancy/vmcnt/phasing/LDS). Fix: block starts K at
//  koff = ((b>>3)+slice*16)&31 and wraps (fp32 acc is order-independent);
//  loop becomes fully uniform (no peel; wrapped prefetches harmless).

#define B_ 256
#define R_ 64
#define F_ 2048
#define H_ 512
#define DIM_ 512

typedef short bf16x8 __attribute__((ext_vector_type(8)));
typedef float f32x4 __attribute__((ext_vector_type(4)));

__device__ __forceinline__ ushort f2bf(float x) {
  __hip_bfloat16 h = __float2bfloat16(x);
  return __builtin_bit_cast(ushort, h);
}

__device__ __forceinline__ uint4 pack8(float4 x, float4 y) {
  uint4 r;
  r.x = (uint)f2bf(x.x) | ((uint)f2bf(x.y) << 16);
  r.y = (uint)f2bf(x.z) | ((uint)f2bf(x.w) << 16);
  r.z = (uint)f2bf(y.x) | ((uint)f2bf(y.y) << 16);
  r.w = (uint)f2bf(y.z) | ((uint)f2bf(y.w) << 16);
  return r;
}

__device__ __forceinline__ void gld16(const float* g, float* l) {
  __builtin_amdgcn_global_load_lds(
      (const __attribute__((address_space(1))) unsigned int*)(g),
      (__attribute__((address_space(3))) unsigned int*)(l),
      16, 0, 0);
}

// blocks [0,4096): wpack[((kt*32+ctg)*64 + g*16 + c)*8 + i] = bf16(W_w[kt*32+g*8+i][ctg*16+c])
// blocks [4096,4352): p'[b][d] = prev[b]@W2_w[:,d] + W2_b[d] + W_b[d]
__global__ __launch_bounds__(256) void setup_k(const float* __restrict__ Ww,
                                               ushort* __restrict__ wpack,
                                               const float* __restrict__ prev,
                                               const float* __restrict__ W2w,
                                               const float* __restrict__ W2b,
                                               const float* __restrict__ Wb,
                                               float* __restrict__ pprime) {
  __shared__ float lprev[8][H_];
  if (blockIdx.x < 4096) {
    int idx = blockIdx.x * 256 + threadIdx.x;
    float v = Ww[idx];
    int k = idx >> 9;
    int d = idx & 511;
    int kt = k >> 5, kr = k & 31;
    int g = kr >> 3, i = kr & 7;
    int ctg = d >> 4, c = d & 15;
    size_t dst = ((size_t)((kt * 32 + ctg) * 64 + g * 16 + c)) * 8 + (size_t)i;
    wpack[dst] = f2bf(v);
    return;
  }
  int pb = blockIdx.x - 4096;
  int bg = pb >> 3;
  int d0 = (pb & 7) * 64;
  int t = threadIdx.x;
  const float4* src = reinterpret_cast<const float4*>(prev + (size_t)bg * 8 * H_);
  float4* dst = reinterpret_cast<float4*>(&lprev[0][0]);
  for (int i = t; i < 8 * H_ / 4; i += 256) dst[i] = src[i];
  __syncthreads();
  int d = d0 + (t & 63);
  int bq = t >> 6;
  float a0 = 0.f, a1 = 0.f;
  #pragma unroll 8
  for (int h = 0; h < H_; ++h) {
    float wv = W2w[h * DIM_ + d];
    a0 += lprev[bq][h] * wv;
    a1 += lprev[bq + 4][h] * wv;
  }
  float bias = W2b[d] + Wb[d];
  pprime[(size_t)(bg * 8 + bq) * DIM_ + d] = a0 + bias;
  pprime[(size_t)(bg * 8 + bq + 4) * DIM_ + d] = a1 + bias;
}

__device__ __forceinline__ float fast_tanh(float x) {
  float e = __expf(2.f * x);
  return 1.f - 2.f / (e + 1.f);
}

// sp[b*2+slice][r] = sum_{d in slice's 256 cols} tanh(c[b][r][d]+p'[b][d])*W3[d]
__global__ __launch_bounds__(512, 4) void score_k(const float* __restrict__ feat,
                                                  const ushort* __restrict__ wpack,
                                                  const float* __restrict__ pprime,
                                                  const float* __restrict__ W3,
                                                  float* __restrict__ sp) {
  int slice = blockIdx.x >> 8;          // slice-major: both slices of b same XCD
  int b = blockIdx.x & 255;
  int t = threadIdx.x;
  int wid = t >> 6;                     // 8 waves; wave owns cols [wid*32,+32)
  int l = t & 63;
  int l15 = l & 15, g = l >> 4;
  const float* featB = feat + (size_t)b * R_ * F_;
  int koff = ((b >> 3) + slice * 16) & 31;   // per-block K-rotation

  // raw[buf][row][c16]: holds global 16B-chunk (c16 ^ (row&15))  [src-swizzle]
  __shared__ float raw[3][4096];        // 3 x 16 KB DMA ring
  // frg[buf][kc*64 + (row ^ ((kc*2)&15))] = bf16 A[row][k=kc*8..+8]
  __shared__ uint4 frg[2][512];         // 2 x 8 KB
  __shared__ float lds_part[8][R_];

  f32x4 acc[4][2];
  #pragma unroll
  for (int rt = 0; rt < 4; ++rt)
    #pragma unroll
    for (int ct = 0; ct < 2; ++ct)
      acc[rt][ct] = (f32x4){0.f, 0.f, 0.f, 0.f};

  // ---- DMA geometry: wave wid covers rows [wid*4, wid*4+4) and +32
  int srow = wid * 4 + g;
  int sch = l15 ^ (srow & 15);
  const float* sg0 = featB + (size_t)srow * F_ + sch * 4;
  const float* sg1 = featB + (size_t)(srow + 32) * F_ + sch * 4;

  // ---- cvt geometry: thread t -> row t>>3, k-chunk pair cj2 = (t&7)*2
  int crow = t >> 3, cj2 = (t & 7) * 2;
  int rm = crow & 15;
  int cw = (t & 7) * 64 + (crow ^ cj2);

  // ---- B pointer: frag(kt,s,ct) at wp + kt*32768 + s*16384 + ct*512 (ushorts)
  const ushort* wp = wpack + (size_t)(slice * 16 + wid * 2) * 512 + (size_t)l * 8;

#define STAGE(buf, kt) do {                                        \
    gld16(sg0 + (size_t)(kt) * 64, &raw[buf][wid * 256]);          \
    gld16(sg1 + (size_t)(kt) * 64, &raw[buf][2048 + wid * 256]);   \
  } while (0)

#define LOADB(dst, kt) do {                                        \
    const ushort* wpk_ = wp + (size_t)(kt) * 32768;                \
    dst[0][0] = *reinterpret_cast<const uint4*>(wpk_);             \
    dst[0][1] = *reinterpret_cast<const uint4*>(wpk_ + 512);       \
    dst[1][0] = *reinterpret_cast<const uint4*>(wpk_ + 16384);     \
    dst[1][1] = *reinterpret_cast<const uint4*>(wpk_ + 16384 + 512); \
  } while (0)

#define CVT(nb, fb) do {                                           \
    const float* rb_ = &raw[nb][crow * 64];                        \
    float4 x_ = *reinterpret_cast<const float4*>(rb_ + ((cj2 + 0) ^ rm) * 4); \
    float4 y_ = *reinterpret_cast<const float4*>(rb_ + ((cj2 + 1) ^ rm) * 4); \
    frg[fb][cw] = pack8(x_, y_);                                   \
  } while (0)

#define MFMA_STEP(fb, BSET) do {                                   \
    _Pragma("unroll")                                              \
    for (int s_ = 0; s_ < 2; ++s_) {                               \
      bf16x8 af_[4];                                               \
      int kc_ = s_ * 4 + g;                                        \
      _Pragma("unroll")                                            \
      for (int rt_ = 0; rt_ < 4; ++rt_)                            \
        af_[rt_] = __builtin_bit_cast(bf16x8,                      \
            frg[fb][kc_ * 64 + ((rt_ * 16 + l15) ^ ((kc_ * 2) & 15))]); \
      _Pragma("unroll")                                            \
      for (int ct_ = 0; ct_ < 2; ++ct_) {                          \
        bf16x8 bv_ = __builtin_bit_cast(bf16x8, BSET[s_][ct_]);    \
        _Pragma("unroll")                                          \
        for (int rt_ = 0; rt_ < 4; ++rt_)                          \
          acc[rt_][ct_] = __builtin_amdgcn_mfma_f32_16x16x32_bf16( \
              af_[rt_], bv_, acc[rt_][ct_], 0, 0, 0);              \
      }                                                            \
    }                                                              \
  } while (0)

#define BARRIER_VM(N) do {                                         \
    asm volatile("s_waitcnt vmcnt(" #N ") lgkmcnt(0)" ::: "memory"); \
    __builtin_amdgcn_s_barrier();                                  \
    asm volatile("" ::: "memory");                                 \
  } while (0)

  uint4 bA[2][2], bB[2][2];
  // prologue: D(k0),D(k1) in flight; bA=B(k0). Drain D(k0); publish raw0.
  STAGE(0, koff);
  STAGE(1, (koff + 1) & 31);
  LOADB(bA, koff);
  asm volatile("s_waitcnt vmcnt(6)" ::: "memory");
  __builtin_amdgcn_s_barrier();
  asm volatile("" ::: "memory");
  STAGE(2, (koff + 2) & 31);
  CVT(0, 0);                            // tile k(0) -> frg[0]

  // fully uniform wrapped loop (wrapped prefetches redundant but harmless)
  int st_b = 0, cv_b = 1;
  #pragma unroll 1
  for (int i = 0; i < 32; i += 2) {
    LOADB(bB, (koff + i + 1) & 31);
    BARRIER_VM(10);
    STAGE(st_b, (koff + i + 3) & 31);
    CVT(cv_b, 1);
    __builtin_amdgcn_s_setprio(1);
    MFMA_STEP(0, bA);
    __builtin_amdgcn_s_setprio(0);
    st_b = (st_b == 2) ? 0 : st_b + 1;
    cv_b = (cv_b == 2) ? 0 : cv_b + 1;
    LOADB(bA, (koff + i + 2) & 31);
    BARRIER_VM(10);
    STAGE(st_b, (koff + i + 4) & 31);
    CVT(cv_b, 0);
    __builtin_amdgcn_s_setprio(1);
    MFMA_STEP(1, bB);
    __builtin_amdgcn_s_setprio(0);
    st_b = (st_b == 2) ? 0 : st_b + 1;
    cv_b = (cv_b == 2) ? 0 : cv_b + 1;
  }

#undef STAGE
#undef LOADB
#undef CVT
#undef MFMA_STEP
#undef BARRIER_VM

  // epilogue: tanh + W3 dot in registers
  // acc[rt][ct][j] = c[row = rt*16 + g*4 + j][col = slice*256 + wid*32 + ct*16 + l15]
  float pp[2], w3v[2];
  #pragma unroll
  for (int ct = 0; ct < 2; ++ct) {
    int col = slice * 256 + wid * 32 + ct * 16 + l15;
    pp[ct] = pprime[b * DIM_ + col];
    w3v[ct] = W3[col];
  }
  #pragma unroll
  for (int rt = 0; rt < 4; ++rt) {
    #pragma unroll
    for (int j = 0; j < 4; ++j) {
      float v = fast_tanh(acc[rt][0][j] + pp[0]) * w3v[0]
              + fast_tanh(acc[rt][1][j] + pp[1]) * w3v[1];
      v += __shfl_xor(v, 1);
      v += __shfl_xor(v, 2);
      v += __shfl_xor(v, 4);
      v += __shfl_xor(v, 8);
      if (l15 == 0) lds_part[wid][rt * 16 + g * 4 + j] = v;
    }
  }
  __syncthreads();

  if (t < R_) {
    float s = 0.f;
    #pragma unroll
    for (int w = 0; w < 8; ++w) s += lds_part[w][t];
    sp[((size_t)b * 2 + slice) * R_ + t] = s;
  }
}

// softmax + weighted sum: grid = B*4, 256 thr, 512 f per block
__global__ __launch_bounds__(256) void wsum_k(const float* __restrict__ feat,
                                              const float* __restrict__ sp,
                                              float* __restrict__ out) {
  int b = blockIdx.x >> 2;
  int f0 = (blockIdx.x & 3) * 512;
  int t = threadIdx.x;
  __shared__ float lds_aw[R_];

  if (t < R_) {
    float s = sp[((size_t)b * 2 + 0) * R_ + t] + sp[((size_t)b * 2 + 1) * R_ + t];
    float m = s;
    #pragma unroll
    for (int off = 32; off >= 1; off >>= 1) m = fmaxf(m, __shfl_xor(m, off));
    float e = __expf(s - m);
    float su = e;
    #pragma unroll
    for (int off = 32; off >= 1; off >>= 1) su += __shfl_xor(su, off);
    lds_aw[t] = e / su;
  }
  __syncthreads();

  const float* fp = feat + (size_t)b * R_ * F_ + f0 + t * 2;
  float qx = 0.f, qy = 0.f;
  #pragma unroll 8
  for (int r = 0; r < R_; ++r) {
    float a = lds_aw[r];
    float2 v = *reinterpret_cast<const float2*>(fp + (size_t)r * F_);
    qx += a * v.x;
    qy += a * v.y;
  }
  *reinterpret_cast<float2*>(out + (size_t)b * F_ + f0 + t * 2) = (float2){qx, qy};
}

extern "C" void kernel_launch(void* const* d_in, const int* in_sizes, int n_in,
                              void* d_out, int out_size, void* d_ws, size_t ws_size,
                              hipStream_t stream) {
  const float* feat = (const float*)d_in[0];   // [B,R,F]
  const float* prev = (const float*)d_in[1];   // [B,H]
  const float* Ww   = (const float*)d_in[2];   // [F,DIM]
  const float* Wb   = (const float*)d_in[3];   // [DIM]
  const float* W2w  = (const float*)d_in[4];   // [H,DIM]
  const float* W2b  = (const float*)d_in[5];   // [DIM]
  const float* W3w  = (const float*)d_in[6];   // [DIM,1]
  // d_in[7] = W3_b: cancels in softmax
  float* out = (float*)d_out;

  ushort* wpack  = (ushort*)d_ws;                                          // 2 MB
  float*  pprime = (float*)((char*)d_ws + (size_t)F_ * DIM_ * 2);          // 512 KB
  float*  sp     = (float*)((char*)d_ws + (size_t)F_ * DIM_ * 2
                                        + (size_t)B_ * DIM_ * 4);          // 128 KB

  setup_k<<<4096 + 256, 256, 0, stream>>>(Ww, wpack, prev, W2w, W2b, Wb, pprime);
  score_k<<<B_ * 2, 512, 0, stream>>>(feat, wpack, pprime, W3w, sp);
  wsum_k<<<B_ * 4, 256, 0, stream>>>(feat, sp, out);
}

// Round 17
// 110.619 us; speedup vs baseline: 1.8054x; 1.0020x over previous
//
#include <hip/hip_runtime.h>
#include <hip/hip_bf16.h>

// attention_84464826843938: additive-attention pooling, MI355X (gfx950)
//
// R17: R13 structure + NON-TEMPORAL A loads (single-variable experiment).
//  Accounting: B(wpack) re-reads = 512 MB/dispatch, served by L3 (FETCH only
//  ~90MB -> not HBM; A-stream 16MB/XCD evicts 2MB wpack from 4MB L2).
//  L3 latency (~700cyc) x limited outstanding lines = ~10 B/cyc/CU B-delivery
//  = the 82us invariant. Every prior experiment (occupancy/vmcnt/phasing/LDS/
//  barrier/rotation) was downstream of this. Fix: A loads nontemporal (nt, no
//  L2 allocation) -> wpack stays L2-resident -> B at ~200cyc/34.5TB/s.
//  Geometry = R13: BM=64 BN=256 BK=64, 256thr/4waves, wave 64rx64c, reg-stage
//  A 2 steps ahead (named sets), B 2 sets alternating, counted vmcnt(12),
//  1 barrier/step, grid 512 slice-major, 2 blocks/CU.

#define B_ 256
#define R_ 64
#define F_ 2048
#define H_ 512
#define DIM_ 512

typedef short bf16x8 __attribute__((ext_vector_type(8)));
typedef float f32x4 __attribute__((ext_vector_type(4)));

__device__ __forceinline__ ushort f2bf(float x) {
  __hip_bfloat16 h = __float2bfloat16(x);
  return __builtin_bit_cast(ushort, h);
}

__device__ __forceinline__ uint2 pack4(float4 x) {
  uint2 r;
  r.x = (uint)f2bf(x.x) | ((uint)f2bf(x.y) << 16);
  r.y = (uint)f2bf(x.z) | ((uint)f2bf(x.w) << 16);
  return r;
}

__device__ __forceinline__ float4 ntload4(const float* p) {
  const __attribute__((ext_vector_type(4))) float* vp =
      reinterpret_cast<const __attribute__((ext_vector_type(4))) float*>(p);
  __attribute__((ext_vector_type(4))) float v = __builtin_nontemporal_load(vp);
  return (float4){v.x, v.y, v.z, v.w};
}

// blocks [0,4096): wpack[((kt*32+ctg)*64 + g*16 + c)*8 + i] = bf16(W_w[kt*32+g*8+i][ctg*16+c])
// blocks [4096,4352): p'[b][d] = prev[b]@W2_w[:,d] + W2_b[d] + W_b[d]
__global__ __launch_bounds__(256) void setup_k(const float* __restrict__ Ww,
                                               ushort* __restrict__ wpack,
                                               const float* __restrict__ prev,
                                               const float* __restrict__ W2w,
                                               const float* __restrict__ W2b,
                                               const float* __restrict__ Wb,
                                               float* __restrict__ pprime) {
  __shared__ float lprev[8][H_];
  if (blockIdx.x < 4096) {
    int idx = blockIdx.x * 256 + threadIdx.x;
    float v = Ww[idx];
    int k = idx >> 9;
    int d = idx & 511;
    int kt = k >> 5, kr = k & 31;
    int g = kr >> 3, i = kr & 7;
    int ctg = d >> 4, c = d & 15;
    size_t dst = ((size_t)((kt * 32 + ctg) * 64 + g * 16 + c)) * 8 + (size_t)i;
    wpack[dst] = f2bf(v);
    return;
  }
  int pb = blockIdx.x - 4096;
  int bg = pb >> 3;
  int d0 = (pb & 7) * 64;
  int t = threadIdx.x;
  const float4* src = reinterpret_cast<const float4*>(prev + (size_t)bg * 8 * H_);
  float4* dst = reinterpret_cast<float4*>(&lprev[0][0]);
  for (int i = t; i < 8 * H_ / 4; i += 256) dst[i] = src[i];
  __syncthreads();
  int d = d0 + (t & 63);
  int bq = t >> 6;
  float a0 = 0.f, a1 = 0.f;
  #pragma unroll 8
  for (int h = 0; h < H_; ++h) {
    float wv = W2w[h * DIM_ + d];
    a0 += lprev[bq][h] * wv;
    a1 += lprev[bq + 4][h] * wv;
  }
  float bias = W2b[d] + Wb[d];
  pprime[(size_t)(bg * 8 + bq) * DIM_ + d] = a0 + bias;
  pprime[(size_t)(bg * 8 + bq + 4) * DIM_ + d] = a1 + bias;
}

__device__ __forceinline__ float fast_tanh(float x) {
  float e = __expf(2.f * x);
  return 1.f - 2.f / (e + 1.f);
}

// sp[b*2+slice][r] = sum_{d in slice's 256 cols} tanh(c[b][r][d]+p'[b][d])*W3[d]
__global__ __launch_bounds__(256, 2) void score_k(const float* __restrict__ feat,
                                                  const ushort* __restrict__ wpack,
                                                  const float* __restrict__ pprime,
                                                  const float* __restrict__ W3,
                                                  float* __restrict__ sp) {
  int slice = blockIdx.x >> 8;          // slice-major: both slices of b same XCD
  int b = blockIdx.x & 255;
  int t = threadIdx.x;
  int wid = t >> 6;                     // 4 waves; wave owns cols [wid*64,+64)
  int l = t & 63;
  int l15 = l & 15, g = l >> 4;
  const float* featB = feat + (size_t)b * R_ * F_;

  // frg[buf][kc*64 + (row ^ kc)] = bf16 A[row][k = kt*64 + kc*8 .. +8]
  __shared__ uint4 frg[2][512];         // 2 x 8 KB double buffer
  __shared__ float lds_part[4][R_];

  f32x4 acc[4][4];
  #pragma unroll
  for (int rt = 0; rt < 4; ++rt)
    #pragma unroll
    for (int ct = 0; ct < 4; ++ct)
      acc[rt][ct] = (f32x4){0.f, 0.f, 0.f, 0.f};

  // ---- A staging: thread t covers float4-chunk c4 = t&15 of rows (t>>4)+16j
  int c4 = t & 15;
  int r16 = t >> 4;
  int kcw = c4 >> 1, half = c4 & 1;
  const float* gaj[4];
  int wij[4];
  #pragma unroll
  for (int j = 0; j < 4; ++j) {
    int r = r16 + 16 * j;
    gaj[j] = featB + (size_t)r * F_ + (size_t)(c4 * 4);
    wij[j] = kcw * 64 + (r ^ kcw);
  }

  // ---- B pointer: frag(kt,s,ct) at wp + kt*32768 + s*16384 + ct*512 (ushorts)
  const ushort* wp = wpack + (size_t)(slice * 16 + wid * 4) * 512 + (size_t)l * 8;

#define LOADA(SET, kt) do {                                          \
    _Pragma("unroll")                                                \
    for (int j_ = 0; j_ < 4; ++j_)                                   \
      SET[j_] = ntload4(gaj[j_] + (size_t)(kt) * 64);                \
  } while (0)

#define CVTW(SET, fb) do {                                           \
    _Pragma("unroll")                                                \
    for (int j_ = 0; j_ < 4; ++j_) {                                 \
      uint2* d_ = reinterpret_cast<uint2*>(&frg[fb][wij[j_]]);       \
      d_[half] = pack4(SET[j_]);                                     \
    }                                                                \
  } while (0)

#define LOADB(dst, kt) do {                                          \
    const ushort* wpk_ = wp + (size_t)(kt) * 32768;                  \
    _Pragma("unroll")                                                \
    for (int s_ = 0; s_ < 2; ++s_)                                   \
      _Pragma("unroll")                                              \
      for (int ct_ = 0; ct_ < 4; ++ct_)                              \
        dst[s_][ct_] = *reinterpret_cast<const uint4*>(              \
            wpk_ + s_ * 16384 + ct_ * 512);                          \
  } while (0)

#define MFMA_STEP(fb, BSET) do {                                     \
    _Pragma("unroll")                                                \
    for (int s_ = 0; s_ < 2; ++s_) {                                 \
      int kc_ = s_ * 4 + g;                                          \
      bf16x8 af_[4];                                                 \
      _Pragma("unroll")                                              \
      for (int rt_ = 0; rt_ < 4; ++rt_)                              \
        af_[rt_] = __builtin_bit_cast(bf16x8,                        \
            frg[fb][kc_ * 64 + ((rt_ * 16 + l15) ^ kc_)]);           \
      _Pragma("unroll")                                              \
      for (int ct_ = 0; ct_ < 4; ++ct_) {                            \
        bf16x8 bv_ = __builtin_bit_cast(bf16x8, BSET[s_][ct_]);      \
        _Pragma("unroll")                                            \
        for (int rt_ = 0; rt_ < 4; ++rt_)                            \
          acc[rt_][ct_] = __builtin_amdgcn_mfma_f32_16x16x32_bf16(   \
              af_[rt_], bv_, acc[rt_][ct_], 0, 0, 0);                \
      }                                                              \
    }                                                                \
  } while (0)

#define WAITBAR(N) do {                                              \
    asm volatile("s_waitcnt vmcnt(" #N ") lgkmcnt(0)" ::: "memory"); \
    __builtin_amdgcn_s_barrier();                                    \
    asm volatile("" ::: "memory");                                   \
  } while (0)

  float4 aS0[4], aS1[4];
  uint4 bA[2][2 * 2], bB[2][2 * 2];

  // prologue: A(0)->aS0, B(0)->bA, A(1)->aS1; drain A(0); cvt -> frg[0]
  LOADA(aS0, 0);
  LOADB(bA, 0);
  LOADA(aS1, 1);
  asm volatile("s_waitcnt vmcnt(12)" ::: "memory");
  CVTW(aS0, 0);

  for (int kt = 0; kt < 28; kt += 2) {
    // even half (tile kt): frg[0], bA
    LOADB(bB, kt + 1);
    LOADA(aS0, kt + 2);
    WAITBAR(12);
    CVTW(aS1, 1);                       // A(kt+1) -> frg[1]
    __builtin_amdgcn_s_setprio(1);
    MFMA_STEP(0, bA);
    __builtin_amdgcn_s_setprio(0);
    // odd half (tile kt+1): frg[1], bB
    LOADB(bA, kt + 2);
    LOADA(aS1, kt + 3);
    WAITBAR(12);
    CVTW(aS0, 0);                       // A(kt+2) -> frg[0]
    __builtin_amdgcn_s_setprio(1);
    MFMA_STEP(1, bB);
    __builtin_amdgcn_s_setprio(0);
  }
  // peel kt=28..31
  LOADB(bB, 29);
  LOADA(aS0, 30);
  WAITBAR(12);
  CVTW(aS1, 1);
  __builtin_amdgcn_s_setprio(1);
  MFMA_STEP(0, bA);
  __builtin_amdgcn_s_setprio(0);

  LOADB(bA, 30);
  LOADA(aS1, 31);
  WAITBAR(12);
  CVTW(aS0, 0);
  __builtin_amdgcn_s_setprio(1);
  MFMA_STEP(1, bB);
  __builtin_amdgcn_s_setprio(0);

  LOADB(bB, 31);
  WAITBAR(8);                           // queue: A(31):4, B(30):8, B(31):8
  CVTW(aS1, 1);
  __builtin_amdgcn_s_setprio(1);
  MFMA_STEP(0, bA);
  __builtin_amdgcn_s_setprio(0);

  WAITBAR(0);
  __builtin_amdgcn_s_setprio(1);
  MFMA_STEP(1, bB);
  __builtin_amdgcn_s_setprio(0);

#undef LOADA
#undef CVTW
#undef LOADB
#undef MFMA_STEP
#undef WAITBAR

  // epilogue: tanh + W3 dot in registers
  // acc[rt][ct][j] = c[row = rt*16 + g*4 + j][col = slice*256 + wid*64 + ct*16 + l15]
  float pp[4], w3v[4];
  #pragma unroll
  for (int ct = 0; ct < 4; ++ct) {
    int col = slice * 256 + wid * 64 + ct * 16 + l15;
    pp[ct] = pprime[b * DIM_ + col];
    w3v[ct] = W3[col];
  }
  #pragma unroll
  for (int rt = 0; rt < 4; ++rt) {
    #pragma unroll
    for (int j = 0; j < 4; ++j) {
      float v = fast_tanh(acc[rt][0][j] + pp[0]) * w3v[0]
              + fast_tanh(acc[rt][1][j] + pp[1]) * w3v[1]
              + fast_tanh(acc[rt][2][j] + pp[2]) * w3v[2]
              + fast_tanh(acc[rt][3][j] + pp[3]) * w3v[3];
      v += __shfl_xor(v, 1);
      v += __shfl_xor(v, 2);
      v += __shfl_xor(v, 4);
      v += __shfl_xor(v, 8);
      if (l15 == 0) lds_part[wid][rt * 16 + g * 4 + j] = v;
    }
  }
  __syncthreads();

  if (t < R_) {
    float s = lds_part[0][t] + lds_part[1][t] + lds_part[2][t] + lds_part[3][t];
    sp[((size_t)b * 2 + slice) * R_ + t] = s;
  }
}

// softmax + weighted sum: grid = B*4, 256 thr, 512 f per block
__global__ __launch_bounds__(256) void wsum_k(const float* __restrict__ feat,
                                              const float* __restrict__ sp,
                                              float* __restrict__ out) {
  int b = blockIdx.x >> 2;
  int f0 = (blockIdx.x & 3) * 512;
  int t = threadIdx.x;
  __shared__ float lds_aw[R_];

  if (t < R_) {
    float s = sp[((size_t)b * 2 + 0) * R_ + t] + sp[((size_t)b * 2 + 1) * R_ + t];
    float m = s;
    #pragma unroll
    for (int off = 32; off >= 1; off >>= 1) m = fmaxf(m, __shfl_xor(m, off));
    float e = __expf(s - m);
    float su = e;
    #pragma unroll
    for (int off = 32; off >= 1; off >>= 1) su += __shfl_xor(su, off);
    lds_aw[t] = e / su;
  }
  __syncthreads();

  const float* fp = feat + (size_t)b * R_ * F_ + f0 + t * 2;
  float qx = 0.f, qy = 0.f;
  #pragma unroll 8
  for (int r = 0; r < R_; ++r) {
    float a = lds_aw[r];
    float2 v = *reinterpret_cast<const float2*>(fp + (size_t)r * F_);
    qx += a * v.x;
    qy += a * v.y;
  }
  *reinterpret_cast<float2*>(out + (size_t)b * F_ + f0 + t * 2) = (float2){qx, qy};
}

extern "C" void kernel_launch(void* const* d_in, const int* in_sizes, int n_in,
                              void* d_out, int out_size, void* d_ws, size_t ws_size,
                              hipStream_t stream) {
  const float* feat = (const float*)d_in[0];   // [B,R,F]
  const float* prev = (const float*)d_in[1];   // [B,H]
  const float* Ww   = (const float*)d_in[2];   // [F,DIM]
  const float* Wb   = (const float*)d_in[3];   // [DIM]
  const float* W2w  = (const float*)d_in[4];   // [H,DIM]
  const float* W2b  = (const float*)d_in[5];   // [DIM]
  const float* W3w  = (const float*)d_in[6];   // [DIM,1]
  // d_in[7] = W3_b: cancels in softmax
  float* out = (float*)d_out;

  ushort* wpack  = (ushort*)d_ws;                                          // 2 MB
  float*  pprime = (float*)((char*)d_ws + (size_t)F_ * DIM_ * 2);          // 512 KB
  float*  sp     = (float*)((char*)d_ws + (size_t)F_ * DIM_ * 2
                                        + (size_t)B_ * DIM_ * 4);          // 128 KB

  setup_k<<<4096 + 256, 256, 0, stream>>>(Ww, wpack, prev, W2w, W2b, Wb, pprime);
  score_k<<<B_ * 2, 256, 0, stream>>>(feat, wpack, pprime, W3w, sp);
  wsum_k<<<B_ * 4, 256, 0, stream>>>(feat, sp, out);
}